// Round 3
// baseline (2407.125 us; speedup 1.0000x reference)
//
#include <hip/hip_runtime.h>
#include <math.h>
#include <stddef.h>

// Problem constants (fixed by reference): B=4, S=4096, D=1024
#define BB 4
#define SS 4096
#define DD 1024
#define MM (BB * SS)   // 16384 rows

typedef __attribute__((ext_vector_type(4))) float f32x4;
typedef __attribute__((ext_vector_type(4))) int   i32x4;
typedef __attribute__((ext_vector_type(8))) short short8;

#define EPI_BIAS  0
#define EPI_GELU  1
#define EPI_RESID 2

// ---------------------------------------------------------------------------
// fp32 -> bf16 split helpers (RNE).  v = hi + lo + O(2^-16 * v)
// ---------------------------------------------------------------------------
__device__ __forceinline__ unsigned short f2bf(float f) {
    unsigned u = __builtin_bit_cast(unsigned, f);
    u = (u + 0x7fffu + ((u >> 16) & 1u)) >> 16;
    return (unsigned short)u;
}
__device__ __forceinline__ float bf2f(unsigned short h) {
    unsigned u = ((unsigned)h) << 16;
    return __builtin_bit_cast(float, u);
}

// ---------------------------------------------------------------------------
// Split-bf16 3-pass MFMA GEMM, NT: C[M,N] = A[M,K]*Bw[N,K]^T + bias (+epi)
// Tile 128x128, BK=32, 256 threads = 4 waves, each wave a 64x64 sub-tile of
// 4x4 16x16 fragments. A/B staged fp32->((hi,lo) bf16) into XOR-swizzled LDS.
// acc = hi*hi + lo*hi + hi*lo  (drops lo*lo ~ 2^-16 rel -> fp32-equivalent).
// MFMA mappings (m89/m91-verified family):
//   A frag: lane l holds A[row=l&15][k = 8*(l>>4) + j], j=0..7  (bf16x8)
//   B frag: lane l holds B[col=l&15][k = 8*(l>>4) + j]          (NT weights)
//   C/D:    lane l, reg r -> C[row=(l>>4)*4 + r][col=l&15]
// ---------------------------------------------------------------------------
#define GBK 32

template <int EPI>
__global__ __launch_bounds__(256) void gemm3bf(
    const float* __restrict__ A, const float* __restrict__ Bw,
    const float* __restrict__ bias, const float* __restrict__ resid,
    float* __restrict__ C, int M, int N, int K)
{
    // 4 planes of [128][32] bf16, 8 KB each: Ahi, Alo, Bhi, Blo
    __shared__ __align__(16) short lds[4 * 128 * GBK];
    char* const Ahi = (char*)lds;
    char* const Alo = Ahi + 8192;
    char* const Bhi = Ahi + 16384;
    char* const Blo = Ahi + 24576;

    const int t = threadIdx.x;
    const int lane = t & 63;
    const int wave = t >> 6;
    const int wr = wave >> 1;       // wave row (0..1) -> 64-row band
    const int wc = wave & 1;        // wave col (0..1) -> 64-col band
    const int l15 = lane & 15;
    const int l4  = lane >> 4;

    const int bm = blockIdx.y * 128;
    const int bn = blockIdx.x * 128;

    // ---- staging mapping: thread t loads row (t>>1), 16 floats at k half (t&1)
    const int srow = t >> 1;
    const int sseg = t & 1;
    const float* ap = A  + (size_t)(bm + srow) * K + sseg * 16;
    const float* bp = Bw + (size_t)(bn + srow) * K + sseg * 16;
    // LDS write addresses (two 16B chunks), XOR-swizzled by (row&7)<<4
    const unsigned smask = (unsigned)((srow & 7) << 4);
    const unsigned wb0 = ((unsigned)(srow * 64 + sseg * 32)) ^ smask;
    const unsigned wb1 = ((unsigned)(srow * 64 + sseg * 32 + 16)) ^ smask;

    // ---- fragment read addresses (constant over K loop)
    const unsigned fmask = (unsigned)((l15 & 7) << 4);
    unsigned aoff[4], boff[4];
#pragma unroll
    for (int m = 0; m < 4; ++m)
        aoff[m] = ((unsigned)((wr * 64 + m * 16 + l15) * 64 + l4 * 16)) ^ fmask;
#pragma unroll
    for (int n = 0; n < 4; ++n)
        boff[n] = ((unsigned)((wc * 64 + n * 16 + l15) * 64 + l4 * 16)) ^ fmask;

    f32x4 acc[4][4];
#pragma unroll
    for (int m = 0; m < 4; ++m)
#pragma unroll
        for (int n = 0; n < 4; ++n) acc[m][n] = (f32x4)0.f;

    for (int k0 = 0; k0 < K; k0 += GBK) {
        // global loads (fp32), 16 floats per operand per thread
        const float4 av0 = ((const float4*)ap)[0];
        const float4 av1 = ((const float4*)ap)[1];
        const float4 av2 = ((const float4*)ap)[2];
        const float4 av3 = ((const float4*)ap)[3];
        const float4 bv0 = ((const float4*)bp)[0];
        const float4 bv1 = ((const float4*)bp)[1];
        const float4 bv2 = ((const float4*)bp)[2];
        const float4 bv3 = ((const float4*)bp)[3];
        ap += GBK; bp += GBK;

        __syncthreads();   // prior iteration's fragment reads complete

        // convert + pack + swizzled LDS writes
        {
            float fa[16] = {av0.x, av0.y, av0.z, av0.w, av1.x, av1.y, av1.z, av1.w,
                            av2.x, av2.y, av2.z, av2.w, av3.x, av3.y, av3.z, av3.w};
            float fb[16] = {bv0.x, bv0.y, bv0.z, bv0.w, bv1.x, bv1.y, bv1.z, bv1.w,
                            bv2.x, bv2.y, bv2.z, bv2.w, bv3.x, bv3.y, bv3.z, bv3.w};
            int ah[8], al[8], bh[8], bl[8];
#pragma unroll
            for (int j = 0; j < 8; ++j) {
                unsigned short h0 = f2bf(fa[2 * j]);
                unsigned short h1 = f2bf(fa[2 * j + 1]);
                unsigned short g0 = f2bf(fa[2 * j] - bf2f(h0));
                unsigned short g1 = f2bf(fa[2 * j + 1] - bf2f(h1));
                ah[j] = (int)((unsigned)h0 | ((unsigned)h1 << 16));
                al[j] = (int)((unsigned)g0 | ((unsigned)g1 << 16));
                h0 = f2bf(fb[2 * j]);
                h1 = f2bf(fb[2 * j + 1]);
                g0 = f2bf(fb[2 * j] - bf2f(h0));
                g1 = f2bf(fb[2 * j + 1] - bf2f(h1));
                bh[j] = (int)((unsigned)h0 | ((unsigned)h1 << 16));
                bl[j] = (int)((unsigned)g0 | ((unsigned)g1 << 16));
            }
            *(i32x4*)(Ahi + wb0) = i32x4{ah[0], ah[1], ah[2], ah[3]};
            *(i32x4*)(Ahi + wb1) = i32x4{ah[4], ah[5], ah[6], ah[7]};
            *(i32x4*)(Alo + wb0) = i32x4{al[0], al[1], al[2], al[3]};
            *(i32x4*)(Alo + wb1) = i32x4{al[4], al[5], al[6], al[7]};
            *(i32x4*)(Bhi + wb0) = i32x4{bh[0], bh[1], bh[2], bh[3]};
            *(i32x4*)(Bhi + wb1) = i32x4{bh[4], bh[5], bh[6], bh[7]};
            *(i32x4*)(Blo + wb0) = i32x4{bl[0], bl[1], bl[2], bl[3]};
            *(i32x4*)(Blo + wb1) = i32x4{bl[4], bl[5], bl[6], bl[7]};
        }
        __syncthreads();

        // fragments + 3-pass MFMA
        short8 fah[4], fal[4];
#pragma unroll
        for (int m = 0; m < 4; ++m) {
            fah[m] = *(const short8*)(Ahi + aoff[m]);
            fal[m] = *(const short8*)(Alo + aoff[m]);
        }
#pragma unroll
        for (int n = 0; n < 4; ++n) {
            const short8 fbh = *(const short8*)(Bhi + boff[n]);
            const short8 fbl = *(const short8*)(Blo + boff[n]);
#pragma unroll
            for (int m = 0; m < 4; ++m) {
                acc[m][n] = __builtin_amdgcn_mfma_f32_16x16x32_bf16(
                    fah[m], fbh, acc[m][n], 0, 0, 0);
                acc[m][n] = __builtin_amdgcn_mfma_f32_16x16x32_bf16(
                    fal[m], fbh, acc[m][n], 0, 0, 0);
                acc[m][n] = __builtin_amdgcn_mfma_f32_16x16x32_bf16(
                    fah[m], fbl, acc[m][n], 0, 0, 0);
            }
        }
    }

    // ---- epilogue: C[row=(l>>4)*4+r][col=l&15] per fragment
#pragma unroll
    for (int n = 0; n < 4; ++n) {
        const int col = bn + wc * 64 + n * 16 + l15;
        const float bvn = bias[col];
#pragma unroll
        for (int m = 0; m < 4; ++m) {
            const int row0 = bm + wr * 64 + m * 16 + l4 * 4;
#pragma unroll
            for (int r = 0; r < 4; ++r) {
                float v = acc[m][n][r] + bvn;
                if (EPI == EPI_GELU)
                    v = 0.5f * v * (1.0f + erff(v * 0.70710678118654752f));
                if (EPI == EPI_RESID)
                    v += resid[(size_t)(row0 + r) * N + col];
                C[(size_t)(row0 + r) * N + col] = v;
            }
        }
    }
}

// ---------------------------------------------------------------------------
// (retained for fast revert; not instantiated)  fp32 vector SGEMM, NT.
// ---------------------------------------------------------------------------
template <int EPI>
__global__ __launch_bounds__(256) void sgemm_nt(
    const float* __restrict__ A, const float* __restrict__ Bw,
    const float* __restrict__ bias, const float* __restrict__ resid,
    float* __restrict__ C, int M, int N, int K)
{
    __shared__ __align__(16) float As[16][132];
    __shared__ __align__(16) float Bs[16][132];
    const int tid = threadIdx.x;
    const int tx = tid & 15, ty = tid >> 4;
    const int bm = blockIdx.y * 128, bn = blockIdx.x * 128;
    const int lr = tid >> 2, lc = (tid & 3) * 4;
    const float* Ap = A + (size_t)(bm + lr) * K + lc;
    const float* Bp = Bw + (size_t)(bn + lr) * K + lc;
    const size_t rstep = (size_t)64 * K;
    float acc[8][8];
#pragma unroll
    for (int i = 0; i < 8; ++i)
#pragma unroll
        for (int j = 0; j < 8; ++j) acc[i][j] = 0.f;
    for (int k0 = 0; k0 < K; k0 += 16) {
        const float4 a0 = *(const float4*)Ap, a1 = *(const float4*)(Ap + rstep);
        const float4 b0 = *(const float4*)Bp, b1 = *(const float4*)(Bp + rstep);
        __syncthreads();
        As[lc + 0][lr] = a0.x; As[lc + 1][lr] = a0.y; As[lc + 2][lr] = a0.z; As[lc + 3][lr] = a0.w;
        As[lc + 0][lr + 64] = a1.x; As[lc + 1][lr + 64] = a1.y; As[lc + 2][lr + 64] = a1.z; As[lc + 3][lr + 64] = a1.w;
        Bs[lc + 0][lr] = b0.x; Bs[lc + 1][lr] = b0.y; Bs[lc + 2][lr] = b0.z; Bs[lc + 3][lr] = b0.w;
        Bs[lc + 0][lr + 64] = b1.x; Bs[lc + 1][lr + 64] = b1.y; Bs[lc + 2][lr + 64] = b1.z; Bs[lc + 3][lr + 64] = b1.w;
        __syncthreads();
#pragma unroll
        for (int k = 0; k < 16; ++k) {
            const float4 av0 = *(const float4*)&As[k][ty * 8];
            const float4 av1 = *(const float4*)&As[k][ty * 8 + 4];
            const float4 bv0 = *(const float4*)&Bs[k][tx * 8];
            const float4 bv1 = *(const float4*)&Bs[k][tx * 8 + 4];
            const float ar[8] = {av0.x, av0.y, av0.z, av0.w, av1.x, av1.y, av1.z, av1.w};
            const float br[8] = {bv0.x, bv0.y, bv0.z, bv0.w, bv1.x, bv1.y, bv1.z, bv1.w};
#pragma unroll
            for (int i = 0; i < 8; ++i)
#pragma unroll
                for (int j = 0; j < 8; ++j) acc[i][j] = fmaf(ar[i], br[j], acc[i][j]);
        }
        Ap += 16; Bp += 16;
    }
#pragma unroll
    for (int i = 0; i < 8; ++i) {
        const int row = bm + ty * 8 + i;
        const size_t off = (size_t)row * N + bn + tx * 8;
#pragma unroll
        for (int j = 0; j < 8; ++j) {
            float v = acc[i][j] + bias[bn + tx * 8 + j];
            if (EPI == EPI_GELU) v = 0.5f * v * (1.0f + erff(v * 0.70710678118654752f));
            if (EPI == EPI_RESID) v += resid[off + j];
            C[off + j] = v;
        }
    }
}

// ---------------------------------------------------------------------------
// Sequence scan kernel for ONE batch: phi = cumsum(omega*exp(ls)/sqrt(pos));
// cm = x*{cos,sin}; mem = cumsum(cm)/pos; ret = rotate(mem, -phi).
// Writes context [SS, 4*DD] for that batch.
// Block: 1024 thr = 16 d-channels x 64 S-chunks(64 elems). Grid: DD/16.
// ---------------------------------------------------------------------------
__global__ __launch_bounds__(1024) void scan_kernel(
    const float* __restrict__ omega, const float* __restrict__ x,
    const float* __restrict__ log_scale, float* __restrict__ ctx)
{
    __shared__ float p_phi[64][16];
    __shared__ float p_r[64][16];
    __shared__ float p_i[64][16];

    const int t = threadIdx.x;
    const int dsub = t & 15;
    const int chunk = t >> 4;               // 0..63, 64 elements each
    const int d = blockIdx.x * 16 + dsub;

    const float esc = expf(log_scale[d]);
    const size_t base = (size_t)chunk * 64 * DD + d;
    const float* om = omega + base;
    const float* xp = x + base;
    float* cb = ctx + (size_t)chunk * 64 * (4 * DD) + d;

    // ---- pass 1: chunk sums of omega_scaled -> phi offsets ----
    float run = 0.f;
#pragma unroll 4
    for (int i = 0; i < 64; ++i) {
        const int s = chunk * 64 + i;
        run += om[(size_t)i * DD] * esc * rsqrtf((float)(s + 1));
    }
    p_phi[chunk][dsub] = run;
    __syncthreads();
    if (t < 16) {   // serial exclusive scan over 64 chunks per channel
        float r2 = 0.f;
        for (int c = 0; c < 64; ++c) { const float v = p_phi[c][t]; p_phi[c][t] = r2; r2 += v; }
    }
    __syncthreads();
    const float phi0 = p_phi[chunk][dsub];

    // ---- pass 2: write cm_real/cm_imag, accumulate their chunk sums ----
    float runp = phi0, rr = 0.f, ri = 0.f;
#pragma unroll 4
    for (int i = 0; i < 64; ++i) {
        const int s = chunk * 64 + i;
        runp += om[(size_t)i * DD] * esc * rsqrtf((float)(s + 1));
        float sn, cs;
        sincosf(runp, &sn, &cs);
        const float xr = xp[(size_t)i * DD];
        const float cr = xr * cs, ci = xr * sn;
        cb[(size_t)i * (4 * DD)]      = cr;
        cb[(size_t)i * (4 * DD) + DD] = ci;
        rr += cr; ri += ci;
    }
    p_r[chunk][dsub] = rr;
    p_i[chunk][dsub] = ri;
    __syncthreads();
    if (t < 32) {
        const int dd = t & 15;
        float (*arr)[16] = (t < 16) ? p_r : p_i;
        float r2 = 0.f;
        for (int c = 0; c < 64; ++c) { const float v = arr[c][dd]; arr[c][dd] = r2; r2 += v; }
    }
    __syncthreads();
    const float r0 = p_r[chunk][dsub];
    const float i0 = p_i[chunk][dsub];

    // ---- pass 3: recompute phi/cm, running mem, write ret_real/ret_imag ----
    runp = phi0; rr = r0; ri = i0;
#pragma unroll 4
    for (int i = 0; i < 64; ++i) {
        const int s = chunk * 64 + i;
        runp += om[(size_t)i * DD] * esc * rsqrtf((float)(s + 1));
        float sn, cs;
        sincosf(runp, &sn, &cs);
        const float xr = xp[(size_t)i * DD];
        rr += xr * cs; ri += xr * sn;
        const float inv = 1.0f / (float)(s + 1);
        const float mr = rr * inv, mi = ri * inv;
        cb[(size_t)i * (4 * DD) + 2 * DD] = mr * cs + mi * sn;
        cb[(size_t)i * (4 * DD) + 3 * DD] = mi * cs - mr * sn;
    }
}

// ---------------------------------------------------------------------------
// LayerNorm over rows of width 4*DD = 4096, in place. One block per row.
// ---------------------------------------------------------------------------
__global__ __launch_bounds__(256) void ln_kernel(
    float* __restrict__ h, const float* __restrict__ gamma,
    const float* __restrict__ beta)
{
    const int row = blockIdx.x;
    float* hp = h + (size_t)row * 4096;
    const int t = threadIdx.x;

    float4 v[4];
    float s1 = 0.f, s2 = 0.f;
#pragma unroll
    for (int k = 0; k < 4; ++k) {
        v[k] = *(const float4*)(hp + (size_t)(t + k * 256) * 4);
        s1 += v[k].x + v[k].y + v[k].z + v[k].w;
        s2 += v[k].x * v[k].x + v[k].y * v[k].y + v[k].z * v[k].z + v[k].w * v[k].w;
    }
#pragma unroll
    for (int off = 32; off > 0; off >>= 1) {
        s1 += __shfl_down(s1, off);
        s2 += __shfl_down(s2, off);
    }
    __shared__ float ws1[4], ws2[4];
    const int wid = t >> 6, lane = t & 63;
    if (lane == 0) { ws1[wid] = s1; ws2[wid] = s2; }
    __syncthreads();
    if (t == 0) {
        float a = 0.f, c = 0.f;
        for (int w = 0; w < 4; ++w) { a += ws1[w]; c += ws2[w]; }
        ws1[0] = a; ws2[0] = c;
    }
    __syncthreads();
    const float mean = ws1[0] * (1.f / 4096.f);
    const float var = ws2[0] * (1.f / 4096.f) - mean * mean;
    const float rs = rsqrtf(var + 1e-5f);

#pragma unroll
    for (int k = 0; k < 4; ++k) {
        const size_t c0 = (size_t)(t + k * 256) * 4;
        const float4 g = *(const float4*)(gamma + c0);
        const float4 bt = *(const float4*)(beta + c0);
        float4 o;
        o.x = (v[k].x - mean) * rs * g.x + bt.x;
        o.y = (v[k].y - mean) * rs * g.y + bt.y;
        o.z = (v[k].z - mean) * rs * g.z + bt.z;
        o.w = (v[k].w - mean) * rs * g.w + bt.w;
        *(float4*)(hp + c0) = o;
    }
}

// ---------------------------------------------------------------------------
extern "C" void kernel_launch(void* const* d_in, const int* in_sizes, int n_in,
                              void* d_out, int out_size, void* d_ws, size_t ws_size,
                              hipStream_t stream)
{
    (void)in_sizes; (void)n_in; (void)out_size;
    const float* x         = (const float*)d_in[0];
    const float* W_omega   = (const float*)d_in[1];
    const float* b_omega   = (const float*)d_in[2];
    const float* log_scale = (const float*)d_in[3];
    const float* ln_gamma  = (const float*)d_in[4];
    const float* ln_beta   = (const float*)d_in[5];
    const float* W1        = (const float*)d_in[6];
    const float* b1        = (const float*)d_in[7];
    const float* W2        = (const float*)d_in[8];
    const float* b2        = (const float*)d_in[9];
    float* out = (float*)d_out;

    char* ws = (char*)d_ws;

    // Full-M path needs: ctx 256 MB + (omega|h1 overlay) 128 MB = 384 MB.
    const size_t full_need = (size_t)MM * 4096 * sizeof(float)
                           + (size_t)MM * 2048 * sizeof(float);
    const bool full = ws_size >= full_need;   // constant across calls -> capture-safe

    if (full) {
        float* ctx   = (float*)ws;
        float* omega = (float*)(ws + (size_t)MM * 4096 * sizeof(float));
        float* h1    = omega;

        gemm3bf<EPI_BIAS><<<dim3(DD / 128, MM / 128), dim3(256), 0, stream>>>(
            x, W_omega, b_omega, nullptr, omega, MM, DD, DD);
        for (int b = 0; b < BB; ++b) {
            scan_kernel<<<dim3(DD / 16), dim3(1024), 0, stream>>>(
                omega + (size_t)b * SS * DD, x + (size_t)b * SS * DD, log_scale,
                ctx + (size_t)b * SS * 4096);
        }
        ln_kernel<<<dim3(MM), dim3(256), 0, stream>>>(ctx, ln_gamma, ln_beta);
        gemm3bf<EPI_GELU><<<dim3((2 * DD) / 128, MM / 128), dim3(256), 0, stream>>>(
            ctx, W1, b1, nullptr, h1, MM, 2 * DD, 4 * DD);
        gemm3bf<EPI_RESID><<<dim3(DD / 128, MM / 128), dim3(256), 0, stream>>>(
            h1, W2, b2, x, out, MM, DD, 2 * DD);
    } else {
        // per-batch pipeline: ctx_b @0 (64 MB), omega_b/h1_b overlay @64 MB (32 MB)
        float* ctx_b   = (float*)ws;
        float* omega_b = (float*)(ws + (size_t)SS * 4096 * sizeof(float));
        float* h1_b    = omega_b;

        for (int b = 0; b < BB; ++b) {
            const float* x_b = x + (size_t)b * SS * DD;
            float* out_b = out + (size_t)b * SS * DD;

            gemm3bf<EPI_BIAS><<<dim3(DD / 128, SS / 128), dim3(256), 0, stream>>>(
                x_b, W_omega, b_omega, nullptr, omega_b, SS, DD, DD);
            scan_kernel<<<dim3(DD / 16), dim3(1024), 0, stream>>>(
                omega_b, x_b, log_scale, ctx_b);
            ln_kernel<<<dim3(SS), dim3(256), 0, stream>>>(ctx_b, ln_gamma, ln_beta);
            gemm3bf<EPI_GELU><<<dim3((2 * DD) / 128, SS / 128), dim3(256), 0, stream>>>(
                ctx_b, W1, b1, nullptr, h1_b, SS, 2 * DD, 4 * DD);
            gemm3bf<EPI_RESID><<<dim3(DD / 128, SS / 128), dim3(256), 0, stream>>>(
                h1_b, W2, b2, x_b, out_b, SS, DD, 2 * DD);
        }
    }
}

// Round 4
// 1350.048 us; speedup vs baseline: 1.7830x; 1.7830x over previous
//
#include <hip/hip_runtime.h>
#include <math.h>
#include <stddef.h>

// Problem constants (fixed by reference): B=4, S=4096, D=1024
#define BB 4
#define SS 4096
#define DD 1024

typedef unsigned short u16;
typedef __attribute__((ext_vector_type(4))) float f32x4;
typedef __attribute__((ext_vector_type(8))) short short8;
typedef __attribute__((ext_vector_type(4))) unsigned short u16x4;

#define EPI_BIAS  0
#define EPI_GELU  1
#define EPI_RESID 2

// fp32 -> bf16 (RNE) and back
__device__ __forceinline__ u16 f2bf(float f) {
    unsigned u = __builtin_bit_cast(unsigned, f);
    u = (u + 0x7fffu + ((u >> 16) & 1u)) >> 16;
    return (u16)u;
}
__device__ __forceinline__ float bf2f(u16 h) {
    unsigned u = ((unsigned)h) << 16;
    return __builtin_bit_cast(float, u);
}

// async global->LDS, 16B per lane; LDS dest is wave-uniform base + lane*16
__device__ __forceinline__ void gll16(const void* g, void* l) {
    __builtin_amdgcn_global_load_lds(
        (const __attribute__((address_space(1))) void*)g,
        (__attribute__((address_space(3))) void*)l, 16, 0, 0);
}

// ---------------------------------------------------------------------------
// Pure-bf16 MFMA GEMM, NT: C[M,N] = A[M,K]*B[N,K]^T + bias (+epilogue)
// A,B bf16 row-major (pre-converted). 128x128 tile, BK=64, 4 waves (64x64 each,
// 4x4 frags of 16x16x32). Staging via global_load_lds with pre-swizzled source
// chunk (c ^ (row&7)); ds_read_b128 applies the same XOR -> conflict-free.
// Frag layout (HW-validated in round 3): A lane l = A[row=l&15][k=8*(l>>4)+j];
// C/D lane l reg r -> C[row=(l>>4)*4+r][col=l&15].
// ---------------------------------------------------------------------------
template <int EPI>
__global__ __launch_bounds__(256) void gemm_bf(
    const u16* __restrict__ A, const u16* __restrict__ B,
    const float* __restrict__ bias, const float* __restrict__ resid,
    void* __restrict__ Cout, int M, int N, int K)
{
    __shared__ __align__(16) u16 Asm[128 * 64];   // [row][64 elems = 128B]
    __shared__ __align__(16) u16 Bsm[128 * 64];

    const int t = threadIdx.x;
    const int lane = t & 63;
    const int wave = t >> 6;
    const int wr = wave >> 1, wc = wave & 1;
    const int l15 = lane & 15, l4 = lane >> 4;
    const int bm = blockIdx.y * 128, bn = blockIdx.x * 128;

    // staging lane roles: 8 rows x 8 chunks(16B) per wave-sweep
    const int r8 = lane >> 3, ch = lane & 7;
    const int schunk = ((ch ^ r8) << 3);      // source chunk pre-swizzle (elems)

    // fragment LDS byte offsets (XOR-swizzled), precomputed for ks=0,1
    const unsigned rmask = (unsigned)((l15 & 7) << 4);
    unsigned aoff[4][2], boff[4][2];
#pragma unroll
    for (int m = 0; m < 4; ++m)
#pragma unroll
        for (int ks = 0; ks < 2; ++ks) {
            const unsigned kb = ((((unsigned)ks << 6) | ((unsigned)l4 << 4)) ^ rmask);
            aoff[m][ks] = (unsigned)((wr * 64 + m * 16 + l15) * 128) + kb;
            boff[m][ks] = (unsigned)((wc * 64 + m * 16 + l15) * 128) + kb;
        }

    f32x4 acc[4][4];
#pragma unroll
    for (int m = 0; m < 4; ++m)
#pragma unroll
        for (int n = 0; n < 4; ++n) acc[m][n] = (f32x4)0.f;

    const char* acb = (const char*)Asm;
    const char* bcb = (const char*)Bsm;

    for (int k0 = 0; k0 < K; k0 += 64) {
        __syncthreads();   // prior iteration's ds_reads complete
#pragma unroll
        for (int j = 0; j < 4; ++j) {
            const int rr = (wave * 4 + j) * 8 + r8;
            gll16(A + (size_t)(bm + rr) * K + k0 + schunk, (void*)(Asm + (wave * 4 + j) * 512));
            gll16(B + (size_t)(bn + rr) * K + k0 + schunk, (void*)(Bsm + (wave * 4 + j) * 512));
        }
        __syncthreads();   // vmcnt(0) drain + barrier: LDS tile ready
#pragma unroll
        for (int ks = 0; ks < 2; ++ks) {
            short8 af[4], bfr[4];
#pragma unroll
            for (int m = 0; m < 4; ++m) af[m] = *(const short8*)(acb + aoff[m][ks]);
#pragma unroll
            for (int n = 0; n < 4; ++n) bfr[n] = *(const short8*)(bcb + boff[n][ks]);
#pragma unroll
            for (int n = 0; n < 4; ++n)
#pragma unroll
                for (int m = 0; m < 4; ++m)
                    acc[m][n] = __builtin_amdgcn_mfma_f32_16x16x32_bf16(
                        af[m], bfr[n], acc[m][n], 0, 0, 0);
        }
    }

    // epilogue
#pragma unroll
    for (int n = 0; n < 4; ++n) {
        const int col = bn + wc * 64 + n * 16 + l15;
        const float bvn = bias[col];
#pragma unroll
        for (int m = 0; m < 4; ++m) {
            const int row0 = bm + wr * 64 + m * 16 + l4 * 4;
#pragma unroll
            for (int r = 0; r < 4; ++r) {
                float v = acc[m][n][r] + bvn;
                if (EPI == EPI_GELU) {
                    v = 0.5f * v * (1.0f + erff(v * 0.70710678118654752f));
                    ((u16*)Cout)[(size_t)(row0 + r) * N + col] = f2bf(v);
                } else if (EPI == EPI_RESID) {
                    v += resid[(size_t)(row0 + r) * N + col];
                    ((float*)Cout)[(size_t)(row0 + r) * N + col] = v;
                } else {
                    ((float*)Cout)[(size_t)(row0 + r) * N + col] = v;
                }
            }
        }
    }
}

// ---------------------------------------------------------------------------
// fp32 -> bf16 plane conversion (grid-stride); optionally zero the LN stats
// buffer from block 0 (stats consumed by the later scan kernel - no race).
// ---------------------------------------------------------------------------
__global__ __launch_bounds__(256) void conv_hi(
    const float* __restrict__ s, u16* __restrict__ d, int n4,
    float* __restrict__ zstats)
{
    if (zstats != nullptr && blockIdx.x == 0) {
        for (int i = threadIdx.x; i < SS * 2; i += 256) zstats[i] = 0.f;
    }
    const int stride = gridDim.x * 256;
    for (int i = blockIdx.x * 256 + threadIdx.x; i < n4; i += stride) {
        const float4 v = ((const float4*)s)[i];
        u16x4 o = {f2bf(v.x), f2bf(v.y), f2bf(v.z), f2bf(v.w)};
        ((u16x4*)d)[i] = o;
    }
}

// ---------------------------------------------------------------------------
// Scan for ONE batch: phi = cumsum(omega*exp(ls)/sqrt(pos)); cm = x*{cos,sin};
// mem = cumsum(cm)/pos; ret = rotate(mem,-phi). Writes ctxH [SS,4096] bf16
// (unnormalized) + per-row LN stats (sum, sumsq over all 4096 cols) via
// 16-lane shfl reduce + atomicAdd. Block: 16 d-channels x 64 chunks of 64.
// ---------------------------------------------------------------------------
__global__ __launch_bounds__(1024) void scan_kernel(
    const float* __restrict__ omega, const float* __restrict__ x,
    const float* __restrict__ log_scale, u16* __restrict__ ctxH,
    float* __restrict__ stats)
{
    __shared__ float p_phi[64][16];
    __shared__ float p_r[64][16];
    __shared__ float p_i[64][16];

    const int t = threadIdx.x;
    const int dsub = t & 15;
    const int chunk = t >> 4;
    const int d = blockIdx.x * 16 + dsub;

    const float esc = expf(log_scale[d]);
    const size_t base = (size_t)chunk * 64 * DD + d;
    const float* om = omega + base;
    const float* xp = x + base;
    u16* cb = ctxH + (size_t)chunk * 64 * 4096 + d;

    // pass 1: chunk sums of omega_scaled
    float run = 0.f;
#pragma unroll 4
    for (int i = 0; i < 64; ++i) {
        const int s = chunk * 64 + i;
        run += om[(size_t)i * DD] * esc * rsqrtf((float)(s + 1));
    }
    p_phi[chunk][dsub] = run;
    __syncthreads();
    if (t < 16) {
        float r2 = 0.f;
        for (int c = 0; c < 64; ++c) { const float v = p_phi[c][t]; p_phi[c][t] = r2; r2 += v; }
    }
    __syncthreads();
    const float phi0 = p_phi[chunk][dsub];

    // pass 2: write cm_real/cm_imag (bf16), accumulate chunk sums
    float runp = phi0, rr = 0.f, ri = 0.f;
#pragma unroll 4
    for (int i = 0; i < 64; ++i) {
        const int s = chunk * 64 + i;
        runp += om[(size_t)i * DD] * esc * rsqrtf((float)(s + 1));
        float sn, cs;
        sincosf(runp, &sn, &cs);
        const float xr = xp[(size_t)i * DD];
        const float cr = xr * cs, ci = xr * sn;
        cb[(size_t)i * 4096]      = f2bf(cr);
        cb[(size_t)i * 4096 + DD] = f2bf(ci);
        rr += cr; ri += ci;
    }
    p_r[chunk][dsub] = rr;
    p_i[chunk][dsub] = ri;
    __syncthreads();
    if (t < 32) {
        const int dd = t & 15;
        float (*arr)[16] = (t < 16) ? p_r : p_i;
        float r2 = 0.f;
        for (int c = 0; c < 64; ++c) { const float v = arr[c][dd]; arr[c][dd] = r2; r2 += v; }
    }
    __syncthreads();
    const float r0 = p_r[chunk][dsub];
    const float i0 = p_i[chunk][dsub];

    // pass 3: recompute, write ret (bf16), accumulate LN row-stats
    runp = phi0; rr = r0; ri = i0;
#pragma unroll 2
    for (int i = 0; i < 64; ++i) {
        const int s = chunk * 64 + i;
        runp += om[(size_t)i * DD] * esc * rsqrtf((float)(s + 1));
        float sn, cs;
        sincosf(runp, &sn, &cs);
        const float xr = xp[(size_t)i * DD];
        const float cr = xr * cs, ci = xr * sn;
        rr += cr; ri += ci;
        const float inv = 1.0f / (float)(s + 1);
        const float mr = rr * inv, mi = ri * inv;
        const float rtr = mr * cs + mi * sn;
        const float rti = mi * cs - mr * sn;
        cb[(size_t)i * 4096 + 2 * DD] = f2bf(rtr);
        cb[(size_t)i * 4096 + 3 * DD] = f2bf(rti);
        // row stats: this thread contributes 4 of the row's 4096 columns
        float vs = cr + ci + rtr + rti;
        float vq = cr * cr + ci * ci + rtr * rtr + rti * rti;
#pragma unroll
        for (int o = 1; o < 16; o <<= 1) {
            vs += __shfl_xor(vs, o);
            vq += __shfl_xor(vq, o);
        }
        if (dsub == 0) {
            atomicAdd(&stats[2 * s], vs);
            atomicAdd(&stats[2 * s + 1], vq);
        }
    }
}

// ---------------------------------------------------------------------------
// In-place LN on bf16 ctx rows of width 4096, using precomputed stats.
// ---------------------------------------------------------------------------
__global__ __launch_bounds__(256) void ln_norm(
    u16* __restrict__ ctx, const float* __restrict__ stats,
    const float* __restrict__ gamma, const float* __restrict__ beta)
{
    const int row = blockIdx.x;
    const float mean = stats[2 * row] * (1.f / 4096.f);
    const float var = stats[2 * row + 1] * (1.f / 4096.f) - mean * mean;
    const float rs = rsqrtf(var + 1e-5f);
    u16* rp = ctx + (size_t)row * 4096;
    const int t = threadIdx.x;
#pragma unroll
    for (int it = 0; it < 2; ++it) {
        const int c0 = (t + it * 256) * 8;
        short8 v = *(short8*)(rp + c0);
        const float4 g0 = ((const float4*)(gamma + c0))[0];
        const float4 g1 = ((const float4*)(gamma + c0))[1];
        const float4 b0 = ((const float4*)(beta + c0))[0];
        const float4 b1 = ((const float4*)(beta + c0))[1];
        const float gv[8] = {g0.x, g0.y, g0.z, g0.w, g1.x, g1.y, g1.z, g1.w};
        const float bv[8] = {b0.x, b0.y, b0.z, b0.w, b1.x, b1.y, b1.z, b1.w};
        short8 o;
#pragma unroll
        for (int j = 0; j < 8; ++j) {
            const float f = bf2f((u16)v[j]);
            o[j] = (short)f2bf((f - mean) * rs * gv[j] + bv[j]);
        }
        *(short8*)(rp + c0) = o;
    }
}

// ---------------------------------------------------------------------------
extern "C" void kernel_launch(void* const* d_in, const int* in_sizes, int n_in,
                              void* d_out, int out_size, void* d_ws, size_t ws_size,
                              hipStream_t stream)
{
    (void)in_sizes; (void)n_in; (void)out_size; (void)ws_size;
    const float* x         = (const float*)d_in[0];
    const float* W_omega   = (const float*)d_in[1];
    const float* b_omega   = (const float*)d_in[2];
    const float* log_scale = (const float*)d_in[3];
    const float* ln_gamma  = (const float*)d_in[4];
    const float* ln_beta   = (const float*)d_in[5];
    const float* W1        = (const float*)d_in[6];
    const float* b1        = (const float*)d_in[7];
    const float* W2        = (const float*)d_in[8];
    const float* b2        = (const float*)d_in[9];
    float* out = (float*)d_out;

    // workspace layout (78 MB + 32 KB total; known-safe: ws >= 96 MB):
    //   ctxH  @ 0      : SS*4096 bf16 = 32 MB   (scan -> ln_norm -> GEMM2 A)
    //   omega @ 32 MB  : SS*1024 f32  = 16 MB   (GEMM1 -> scan)
    //   h1H   @ 32 MB  : SS*2048 bf16 = 16 MB   (overlays omega; GEMM2 -> GEMM3 A)
    //   xH    @ 48 MB  : SS*1024 bf16 =  8 MB   (per-batch GEMM1 A)
    //   WomH  @ 56 MB  : 1024*1024 bf16 = 2 MB
    //   W1H   @ 58 MB  : 2048*4096 bf16 = 16 MB
    //   W2H   @ 74 MB  : 1024*2048 bf16 =  4 MB
    //   stats @ 78 MB  : SS*2 f32 = 32 KB
    char* ws = (char*)d_ws;
    u16*   ctxH  = (u16*)ws;
    float* omega = (float*)(ws + (size_t)32 * 1024 * 1024);
    u16*   h1H   = (u16*)omega;
    u16*   xH    = (u16*)(ws + (size_t)48 * 1024 * 1024);
    u16*   WomH  = (u16*)(ws + (size_t)56 * 1024 * 1024);
    u16*   W1H   = (u16*)(ws + (size_t)58 * 1024 * 1024);
    u16*   W2H   = (u16*)(ws + (size_t)74 * 1024 * 1024);
    float* stats = (float*)(ws + (size_t)78 * 1024 * 1024);

    // weights -> bf16 once per call
    conv_hi<<<dim3(512),  dim3(256), 0, stream>>>(W_omega, WomH, (DD * DD) / 4, nullptr);
    conv_hi<<<dim3(2048), dim3(256), 0, stream>>>(W1, W1H, (2 * DD * 4 * DD) / 4, nullptr);
    conv_hi<<<dim3(1024), dim3(256), 0, stream>>>(W2, W2H, (DD * 2 * DD) / 4, nullptr);

    for (int b = 0; b < BB; ++b) {
        const float* x_b = x + (size_t)b * SS * DD;
        float* out_b = out + (size_t)b * SS * DD;

        // x_b -> bf16 (+ zero stats for this batch)
        conv_hi<<<dim3(2048), dim3(256), 0, stream>>>(x_b, xH, (SS * DD) / 4, stats);

        // omega = x_b * W_omega^T + b_omega  (fp32 out)
        gemm_bf<EPI_BIAS><<<dim3(DD / 128, SS / 128), dim3(256), 0, stream>>>(
            xH, WomH, b_omega, nullptr, omega, SS, DD, DD);

        // scan -> ctxH bf16 + LN stats
        scan_kernel<<<dim3(DD / 16), dim3(1024), 0, stream>>>(
            omega, x_b, log_scale, ctxH, stats);

        // in-place LN on ctxH
        ln_norm<<<dim3(SS), dim3(256), 0, stream>>>(ctxH, stats, ln_gamma, ln_beta);

        // h1 = gelu(ctx * W1^T + b1)  (bf16 out)
        gemm_bf<EPI_GELU><<<dim3((2 * DD) / 128, SS / 128), dim3(256), 0, stream>>>(
            ctxH, W1H, b1, nullptr, h1H, SS, 2 * DD, 4 * DD);

        // out = x + h1 * W2^T + b2  (fp32 out)
        gemm_bf<EPI_RESID><<<dim3(DD / 128, SS / 128), dim3(256), 0, stream>>>(
            h1H, W2H, b2, x_b, out_b, SS, DD, 2 * DD);
    }
}

// Round 5
// 1283.605 us; speedup vs baseline: 1.8753x; 1.0518x over previous
//
#include <hip/hip_runtime.h>
#include <math.h>
#include <stddef.h>

// Problem constants (fixed by reference): B=4, S=4096, D=1024
#define BB 4
#define SS 4096
#define DD 1024

typedef unsigned short u16;
typedef __attribute__((ext_vector_type(4))) float f32x4;
typedef __attribute__((ext_vector_type(8))) short short8;
typedef __attribute__((ext_vector_type(4))) unsigned short u16x4;

#define EPI_BIAS  0
#define EPI_GELU  1
#define EPI_RESID 2

// fp32 -> bf16 (RNE) and back
__device__ __forceinline__ u16 f2bf(float f) {
    unsigned u = __builtin_bit_cast(unsigned, f);
    u = (u + 0x7fffu + ((u >> 16) & 1u)) >> 16;
    return (u16)u;
}
__device__ __forceinline__ float bf2f(u16 h) {
    unsigned u = ((unsigned)h) << 16;
    return __builtin_bit_cast(float, u);
}

// async global->LDS, 16B per lane; LDS dest is wave-uniform base + lane*16
__device__ __forceinline__ void gll16(const void* g, void* l) {
    __builtin_amdgcn_global_load_lds(
        (const __attribute__((address_space(1))) void*)g,
        (__attribute__((address_space(3))) void*)l, 16, 0, 0);
}

// ---------------------------------------------------------------------------
// Pure-bf16 MFMA GEMM, NT: C[M,N] = A[M,K]*B[N,K]^T + bias (+epilogue)
// 128x128 tile, BK=64, 4 waves (64x64 each, 4x4 frags of 16x16x32 bf16).
// Staging via global_load_lds, source chunk pre-swizzled (ch ^ row8);
// ds_read_b128 applies the same XOR -> conflict-free (verified: 0 in r4).
// Frag layout (HW-validated r3/r4): A lane l = A[row=l&15][k=8*(l>>4)+j];
// C/D lane l reg r -> C[row=(l>>4)*4+r][col=l&15].
// ---------------------------------------------------------------------------
template <int EPI>
__global__ __launch_bounds__(256) void gemm_bf(
    const u16* __restrict__ A, const u16* __restrict__ B,
    const float* __restrict__ bias, const float* __restrict__ resid,
    void* __restrict__ Cout, int M, int N, int K)
{
    __shared__ __align__(16) u16 Asm[128 * 64];   // [row][64 elems = 128B]
    __shared__ __align__(16) u16 Bsm[128 * 64];

    const int t = threadIdx.x;
    const int lane = t & 63;
    const int wave = t >> 6;
    const int wr = wave >> 1, wc = wave & 1;
    const int l15 = lane & 15, l4 = lane >> 4;
    const int bm = blockIdx.y * 128, bn = blockIdx.x * 128;

    // staging lane roles: 8 rows x 8 chunks(16B) per wave-sweep
    const int r8 = lane >> 3, ch = lane & 7;
    const int schunk = ((ch ^ r8) << 3);      // source chunk pre-swizzle (elems)

    // fragment LDS byte offsets (XOR-swizzled), precomputed for ks=0,1
    const unsigned rmask = (unsigned)((l15 & 7) << 4);
    unsigned aoff[4][2], boff[4][2];
#pragma unroll
    for (int m = 0; m < 4; ++m)
#pragma unroll
        for (int ks = 0; ks < 2; ++ks) {
            const unsigned kb = ((((unsigned)ks << 6) | ((unsigned)l4 << 4)) ^ rmask);
            aoff[m][ks] = (unsigned)((wr * 64 + m * 16 + l15) * 128) + kb;
            boff[m][ks] = (unsigned)((wc * 64 + m * 16 + l15) * 128) + kb;
        }

    f32x4 acc[4][4];
#pragma unroll
    for (int m = 0; m < 4; ++m)
#pragma unroll
        for (int n = 0; n < 4; ++n) acc[m][n] = (f32x4)0.f;

    const char* acb = (const char*)Asm;
    const char* bcb = (const char*)Bsm;

    for (int k0 = 0; k0 < K; k0 += 64) {
        __syncthreads();   // prior iteration's ds_reads complete
#pragma unroll
        for (int j = 0; j < 4; ++j) {
            const int rr = (wave * 4 + j) * 8 + r8;
            gll16(A + (size_t)(bm + rr) * K + k0 + schunk, (void*)(Asm + (wave * 4 + j) * 512));
            gll16(B + (size_t)(bn + rr) * K + k0 + schunk, (void*)(Bsm + (wave * 4 + j) * 512));
        }
        __syncthreads();   // vmcnt(0) drain + barrier: LDS tile ready
#pragma unroll
        for (int ks = 0; ks < 2; ++ks) {
            short8 af[4], bfr[4];
#pragma unroll
            for (int m = 0; m < 4; ++m) af[m] = *(const short8*)(acb + aoff[m][ks]);
#pragma unroll
            for (int n = 0; n < 4; ++n) bfr[n] = *(const short8*)(bcb + boff[n][ks]);
#pragma unroll
            for (int n = 0; n < 4; ++n)
#pragma unroll
                for (int m = 0; m < 4; ++m)
                    acc[m][n] = __builtin_amdgcn_mfma_f32_16x16x32_bf16(
                        af[m], bfr[n], acc[m][n], 0, 0, 0);
        }
    }

    // epilogue
#pragma unroll
    for (int n = 0; n < 4; ++n) {
        const int col = bn + wc * 64 + n * 16 + l15;
        const float bvn = bias[col];
#pragma unroll
        for (int m = 0; m < 4; ++m) {
            const int row0 = bm + wr * 64 + m * 16 + l4 * 4;
#pragma unroll
            for (int r = 0; r < 4; ++r) {
                float v = acc[m][n][r] + bvn;
                if (EPI == EPI_GELU) {
                    v = 0.5f * v * (1.0f + erff(v * 0.70710678118654752f));
                    ((u16*)Cout)[(size_t)(row0 + r) * N + col] = f2bf(v);
                } else if (EPI == EPI_RESID) {
                    v += resid[(size_t)(row0 + r) * N + col];
                    ((float*)Cout)[(size_t)(row0 + r) * N + col] = v;
                } else {
                    ((float*)Cout)[(size_t)(row0 + r) * N + col] = v;
                }
            }
        }
    }
}

// ---------------------------------------------------------------------------
// fp32 -> bf16 plane conversion (grid-stride, float4/u16x4).
// ---------------------------------------------------------------------------
__global__ __launch_bounds__(256) void conv_hi(
    const float* __restrict__ s, u16* __restrict__ d, int n4)
{
    const int stride = gridDim.x * 256;
    for (int i = blockIdx.x * 256 + threadIdx.x; i < n4; i += stride) {
        const float4 v = ((const float4*)s)[i];
        u16x4 o = {f2bf(v.x), f2bf(v.y), f2bf(v.z), f2bf(v.w)};
        ((u16x4*)d)[i] = o;
    }
}

__global__ __launch_bounds__(256) void zero_f32(float* __restrict__ p, int n)
{
    const int stride = gridDim.x * 256;
    for (int i = blockIdx.x * 256 + threadIdx.x; i < n; i += stride) p[i] = 0.f;
}

// ---------------------------------------------------------------------------
// Scan for ONE batch: phi = cumsum(omega*exp(ls)/sqrt(pos)); cm = x*{cos,sin};
// mem = cumsum(cm)/pos; ret = rotate(mem,-phi). Writes ctxH [SS,4096] bf16
// (unnormalized) + per-row LN stats (sum, sumsq) via 16-lane shfl + atomicAdd.
// Block: 16 d-channels x 64 chunks of 64. Grid: DD/16.
// ---------------------------------------------------------------------------
__global__ __launch_bounds__(1024) void scan_kernel(
    const float* __restrict__ omega, const float* __restrict__ x,
    const float* __restrict__ log_scale, u16* __restrict__ ctxH,
    float* __restrict__ stats)
{
    __shared__ float p_phi[64][16];
    __shared__ float p_r[64][16];
    __shared__ float p_i[64][16];

    const int t = threadIdx.x;
    const int dsub = t & 15;
    const int chunk = t >> 4;
    const int d = blockIdx.x * 16 + dsub;

    const float esc = expf(log_scale[d]);
    const size_t base = (size_t)chunk * 64 * DD + d;
    const float* om = omega + base;
    const float* xp = x + base;
    u16* cb = ctxH + (size_t)chunk * 64 * 4096 + d;

    // pass 1: chunk sums of omega_scaled
    float run = 0.f;
#pragma unroll 4
    for (int i = 0; i < 64; ++i) {
        const int s = chunk * 64 + i;
        run += om[(size_t)i * DD] * esc * rsqrtf((float)(s + 1));
    }
    p_phi[chunk][dsub] = run;
    __syncthreads();
    if (t < 16) {
        float r2 = 0.f;
        for (int c = 0; c < 64; ++c) { const float v = p_phi[c][t]; p_phi[c][t] = r2; r2 += v; }
    }
    __syncthreads();
    const float phi0 = p_phi[chunk][dsub];

    // pass 2: write cm_real/cm_imag (bf16), accumulate chunk sums
    float runp = phi0, rr = 0.f, ri = 0.f;
#pragma unroll 4
    for (int i = 0; i < 64; ++i) {
        const int s = chunk * 64 + i;
        runp += om[(size_t)i * DD] * esc * rsqrtf((float)(s + 1));
        float sn, cs;
        sincosf(runp, &sn, &cs);
        const float xr = xp[(size_t)i * DD];
        const float cr = xr * cs, ci = xr * sn;
        cb[(size_t)i * 4096]      = f2bf(cr);
        cb[(size_t)i * 4096 + DD] = f2bf(ci);
        rr += cr; ri += ci;
    }
    p_r[chunk][dsub] = rr;
    p_i[chunk][dsub] = ri;
    __syncthreads();
    if (t < 32) {
        const int dd = t & 15;
        float (*arr)[16] = (t < 16) ? p_r : p_i;
        float r2 = 0.f;
        for (int c = 0; c < 64; ++c) { const float v = arr[c][dd]; arr[c][dd] = r2; r2 += v; }
    }
    __syncthreads();
    const float r0 = p_r[chunk][dsub];
    const float i0 = p_i[chunk][dsub];

    // pass 3: recompute, write ret (bf16), accumulate LN row-stats
    runp = phi0; rr = r0; ri = i0;
#pragma unroll 2
    for (int i = 0; i < 64; ++i) {
        const int s = chunk * 64 + i;
        runp += om[(size_t)i * DD] * esc * rsqrtf((float)(s + 1));
        float sn, cs;
        sincosf(runp, &sn, &cs);
        const float xr = xp[(size_t)i * DD];
        const float cr = xr * cs, ci = xr * sn;
        rr += cr; ri += ci;
        const float inv = 1.0f / (float)(s + 1);
        const float mr = rr * inv, mi = ri * inv;
        const float rtr = mr * cs + mi * sn;
        const float rti = mi * cs - mr * sn;
        cb[(size_t)i * 4096 + 2 * DD] = f2bf(rtr);
        cb[(size_t)i * 4096 + 3 * DD] = f2bf(rti);
        // row stats: this thread contributes 4 of the row's 4096 columns
        float vs = cr + ci + rtr + rti;
        float vq = cr * cr + ci * ci + rtr * rtr + rti * rti;
#pragma unroll
        for (int o = 1; o < 16; o <<= 1) {
            vs += __shfl_xor(vs, o);
            vq += __shfl_xor(vq, o);
        }
        if (dsub == 0) {
            atomicAdd(&stats[2 * s], vs);
            atomicAdd(&stats[2 * s + 1], vq);
        }
    }
}

// ---------------------------------------------------------------------------
// In-place LN on bf16 ctx rows of width 4096, using precomputed stats.
// ---------------------------------------------------------------------------
__global__ __launch_bounds__(256) void ln_norm(
    u16* __restrict__ ctx, const float* __restrict__ stats,
    const float* __restrict__ gamma, const float* __restrict__ beta)
{
    const int row = blockIdx.x;
    const float mean = stats[2 * row] * (1.f / 4096.f);
    const float var = stats[2 * row + 1] * (1.f / 4096.f) - mean * mean;
    const float rs = rsqrtf(var + 1e-5f);
    u16* rp = ctx + (size_t)row * 4096;
    const int t = threadIdx.x;
#pragma unroll
    for (int it = 0; it < 2; ++it) {
        const int c0 = (t + it * 256) * 8;
        short8 v = *(short8*)(rp + c0);
        const float4 g0 = ((const float4*)(gamma + c0))[0];
        const float4 g1 = ((const float4*)(gamma + c0))[1];
        const float4 b0 = ((const float4*)(beta + c0))[0];
        const float4 b1 = ((const float4*)(beta + c0))[1];
        const float gv[8] = {g0.x, g0.y, g0.z, g0.w, g1.x, g1.y, g1.z, g1.w};
        const float bv[8] = {b0.x, b0.y, b0.z, b0.w, b1.x, b1.y, b1.z, b1.w};
        short8 o;
#pragma unroll
        for (int j = 0; j < 8; ++j) {
            const float f = bf2f((u16)v[j]);
            o[j] = (short)f2bf((f - mean) * rs * gv[j] + bv[j]);
        }
        *(short8*)(rp + c0) = o;
    }
}

// ---------------------------------------------------------------------------
// Batch-group pipeline. G = batches per GEMM group, chosen from ws_size
// (deterministic across calls -> graph-capture-safe).
//   need(G) = ctx G*32MB + h1 G*16MB (omega 16MB overlays) + xHb 8MB
//           + weights 22MB + stats G*32KB  ->  G=4: ~222MB, G=2: ~126MB,
//           G=1: ~78MB (known-safe: r3/r4 ran with >=78MB).
// ---------------------------------------------------------------------------
extern "C" void kernel_launch(void* const* d_in, const int* in_sizes, int n_in,
                              void* d_out, int out_size, void* d_ws, size_t ws_size,
                              hipStream_t stream)
{
    (void)in_sizes; (void)n_in; (void)out_size;
    const float* x         = (const float*)d_in[0];
    const float* W_omega   = (const float*)d_in[1];
    const float* b_omega   = (const float*)d_in[2];
    const float* log_scale = (const float*)d_in[3];
    const float* ln_gamma  = (const float*)d_in[4];
    const float* ln_beta   = (const float*)d_in[5];
    const float* W1        = (const float*)d_in[6];
    const float* b1        = (const float*)d_in[7];
    const float* W2        = (const float*)d_in[8];
    const float* b2        = (const float*)d_in[9];
    float* out = (float*)d_out;

    const size_t MB1 = 1024 * 1024;
    // choose group size
    int G = 1;
    {
        const size_t need4 = (size_t)(4 * 48 + 30 + 1) * MB1;   // ~223 MB
        const size_t need2 = (size_t)(2 * 48 + 30 + 1) * MB1;   // ~127 MB
        if (ws_size >= need4) G = 4;
        else if (ws_size >= need2) G = 2;
    }

    char* ws = (char*)d_ws;
    u16*   ctxH  = (u16*)ws;                                      // G*32 MB
    u16*   h1H   = (u16*)(ws + (size_t)G * 32 * MB1);             // G*16 MB
    float* omega = (float*)h1H;                                   // 16 MB overlay
    u16*   xHb   = (u16*)(ws + (size_t)G * 48 * MB1);             // 8 MB
    u16*   WomH  = (u16*)(ws + (size_t)G * 48 * MB1 + 8 * MB1);   // 2 MB
    u16*   W1H   = (u16*)(ws + (size_t)G * 48 * MB1 + 10 * MB1);  // 16 MB
    u16*   W2H   = (u16*)(ws + (size_t)G * 48 * MB1 + 26 * MB1);  // 4 MB
    float* stats = (float*)(ws + (size_t)G * 48 * MB1 + 30 * MB1);// G*32 KB

    // weights -> bf16 once per call
    conv_hi<<<dim3(512),  dim3(256), 0, stream>>>(W_omega, WomH, (DD * DD) / 4);
    conv_hi<<<dim3(2048), dim3(256), 0, stream>>>(W1, W1H, (2 * DD * 4 * DD) / 4);
    conv_hi<<<dim3(1024), dim3(256), 0, stream>>>(W2, W2H, (DD * 2 * DD) / 4);

    for (int g0 = 0; g0 < BB; g0 += G) {
        const int Mg = G * SS;
        zero_f32<<<dim3(32), dim3(256), 0, stream>>>(stats, Mg * 2);

        for (int bi = 0; bi < G; ++bi) {
            const int b = g0 + bi;
            const float* x_b = x + (size_t)b * SS * DD;

            conv_hi<<<dim3(2048), dim3(256), 0, stream>>>(x_b, xHb, (SS * DD) / 4);
            // omega = x_b * W_omega^T + b_omega  (fp32, overlays h1H region)
            gemm_bf<EPI_BIAS><<<dim3(DD / 128, SS / 128), dim3(256), 0, stream>>>(
                xHb, WomH, b_omega, nullptr, omega, SS, DD, DD);
            // scan -> ctxH slice (bf16) + LN stats slice
            scan_kernel<<<dim3(DD / 16), dim3(1024), 0, stream>>>(
                omega, x_b, log_scale,
                ctxH + (size_t)bi * SS * 4096, stats + (size_t)bi * SS * 2);
        }

        // in-place LN over the whole group
        ln_norm<<<dim3(Mg), dim3(256), 0, stream>>>(ctxH, stats, ln_gamma, ln_beta);

        // h1 = gelu(ctx * W1^T + b1)  (bf16; omega region is dead by now)
        gemm_bf<EPI_GELU><<<dim3((2 * DD) / 128, Mg / 128), dim3(256), 0, stream>>>(
            ctxH, W1H, b1, nullptr, h1H, Mg, 2 * DD, 4 * DD);

        // out = x + h1 * W2^T + b2  (fp32)
        gemm_bf<EPI_RESID><<<dim3(DD / 128, Mg / 128), dim3(256), 0, stream>>>(
            h1H, W2H, b2, x + (size_t)g0 * SS * DD, out + (size_t)g0 * SS * DD,
            Mg, DD, 2 * DD);
    }
}